// Round 6
// baseline (533.070 us; speedup 1.0000x reference)
//
#include <hip/hip_runtime.h>

#define BB 32
#define HH 512
#define WW 512
#define HW (HH * WW)
#define NPIX (BB * HH * WW)

#define TW 64            // tile width
#define TH 32            // tile height
// m buffer: mean over [y0-8..y0+39] x [x0-8..x0+71]; 48 rows, 20 live quads
#define MQ 21            // stride in quads
#define MS 84            // stride in floats
#define MR 48
// e buffer: e over [y0-4..y0+35] x [x0-4..x0+67]; 40 rows, 18 live quads
#define EQ 19            // stride in quads
#define ES 76            // stride in floats
#define ER 40

// load 12 consecutive floats (3 quads) from LDS into dst[12]
#define LOADROW12(dst, p4, base)                                              \
    {                                                                         \
        float4 A_ = (p4)[base], B_ = (p4)[(base) + 1], C_ = (p4)[(base) + 2]; \
        (dst)[0] = A_.x; (dst)[1] = A_.y; (dst)[2]  = A_.z; (dst)[3]  = A_.w; \
        (dst)[4] = B_.x; (dst)[5] = B_.y; (dst)[6]  = B_.z; (dst)[7]  = B_.w; \
        (dst)[8] = C_.x; (dst)[9] = C_.y; (dst)[10] = C_.z; (dst)[11] = C_.w; \
    }

// 9x9 blur into acc[4][4]: window rows r0..r0+11, col quads c0..c0+2.
// Sliding 12-row register ring; all reg indices compile-time after unroll.
#define BLUR9(acc, p4, r0, sq, c0)                                            \
    {                                                                         \
        float fw[4][12];                                                      \
        _Pragma("unroll")                                                     \
        for (int j = 0; j < 3; ++j) LOADROW12(fw[j], p4, ((r0) + j) * (sq) + (c0)); \
        _Pragma("unroll")                                                     \
        for (int ky = 0; ky < 9; ++ky) {                                      \
            LOADROW12(fw[(ky + 3) & 3], p4, ((r0) + ky + 3) * (sq) + (c0));   \
            float w[9];                                                       \
            _Pragma("unroll")                                                 \
            for (int kx = 0; kx < 9; ++kx) w[kx] = kw[ky * 9 + kx];           \
            _Pragma("unroll")                                                 \
            for (int my = 0; my < 4; ++my)                                    \
                _Pragma("unroll")                                             \
                for (int kx = 0; kx < 9; ++kx)                                \
                    _Pragma("unroll")                                         \
                    for (int mx = 0; mx < 4; ++mx)                            \
                        acc[my][mx] = fmaf(w[kx], fw[(my + ky) & 3][mx + kx], acc[my][mx]); \
        }                                                                     \
    }

// ---------------------------------------------------------------------------
// k_stats (64x32 tiles): stage m (48x80) -> blur m -> lm interior + e into
// separate e-LDS -> blur e (2x4 micro-tiles) -> sigma + per-tile partial sum.
// m,q,e never touch HBM. LDS 27.6 KB; VGPR capped at 128 (4 blocks/CU).
// ---------------------------------------------------------------------------
__global__ __launch_bounds__(256, 4) void k_stats(const float* __restrict__ x,
                                                  const float* __restrict__ kw,
                                                  float* __restrict__ lm,
                                                  float* __restrict__ sg,
                                                  float* __restrict__ psums) {
    __shared__ float mt[MR * MS];
    __shared__ float et[ER * ES];
    __shared__ float wsum[4];
    const int tx = threadIdx.x, ty = threadIdx.y;     // 16 x 16
    const int tid = ty * 16 + tx;
    const int x0 = blockIdx.x * TW, y0 = blockIdx.y * TH;
    const size_t boff = (size_t)blockIdx.z * HW;
    const float4* x4 = (const float4*)(x + boff * 3);
    float* lmg = lm + boff;

    // ---- P1: stage m over 48 rows x 20 quads (zero outside image) ----
    for (int i = tid; i < MR * 20; i += 256) {
        int r = i / 20, q = i - r * 20;
        int gy = y0 + r - 8, gx = x0 + 4 * q - 8;
        float4 m = make_float4(0.f, 0.f, 0.f, 0.f);
        if (gy >= 0 && gy < HH && gx >= 0 && gx < WW) {
            int go = (gy * WW + gx) >> 2;
            float4 a = x4[3 * go + 0], b = x4[3 * go + 1], c = x4[3 * go + 2];
            const float t = 1.f / 3.f;
            m.x = (a.x + a.y + a.z) * t;
            m.y = (a.w + b.x + b.y) * t;
            m.z = (b.z + b.w + c.x) * t;
            m.w = (c.y + c.z + c.w) * t;
        }
        *(float4*)&mt[r * MS + 4 * q] = m;
    }
    __syncthreads();

    // ---- P2: 180 micro-tiles (10 x 18) of 4x4 over the 40x72 lm/e region;
    // one tile per thread (tid < 180). blur m -> lm write -> e -> e-LDS.
    if (tid < 180) {
        const float4* m4 = (const float4*)mt;
        int tr = tid / 18, q0 = tid - tr * 18;        // tr 0..9, q0 0..17
        float acc[4][4] = {};
        BLUR9(acc, m4, 4 * tr, MQ, q0);
        const int X0 = x0 - 4 + 4 * q0;               // 16B-aligned
        const bool cin = (X0 >= 0) && (X0 < WW);
        const bool wlm = (tr >= 1) && (tr <= 8) && (q0 >= 1) && (q0 <= 16);
#pragma unroll
        for (int row = 0; row < 4; ++row) {
            int Y = y0 - 4 + 4 * tr + row;
            float4 l = make_float4(acc[row][0], acc[row][1], acc[row][2], acc[row][3]);
            if (wlm) *(float4*)(lmg + (size_t)Y * WW + X0) = l;
            float4 e = make_float4(0.f, 0.f, 0.f, 0.f);
            if (cin && Y >= 0 && Y < HH) {
                float4 mm = *(const float4*)&mt[(4 * tr + row + 4) * MS + 4 * q0 + 4];
                int go = (Y * WW + X0) >> 2;
                float4 a = x4[3 * go + 0], b = x4[3 * go + 1], c = x4[3 * go + 2];
                const float t3 = 1.f / 3.f;
                float4 qv;
                qv.x = (a.x * a.x + a.y * a.y + a.z * a.z) * t3;
                qv.y = (a.w * a.w + b.x * b.x + b.y * b.y) * t3;
                qv.z = (b.z * b.z + b.w * b.w + c.x * c.x) * t3;
                qv.w = (c.y * c.y + c.z * c.z + c.w * c.w) * t3;
                e.x = fmaxf(qv.x - l.x * (2.f * mm.x - l.x), 0.f);
                e.y = fmaxf(qv.y - l.y * (2.f * mm.y - l.y), 0.f);
                e.z = fmaxf(qv.z - l.z * (2.f * mm.z - l.z), 0.f);
                e.w = fmaxf(qv.w - l.w * (2.f * mm.w - l.w), 0.f);
            }
            *(float4*)&et[(4 * tr + row) * ES + 4 * q0] = e;
        }
    }
    __syncthreads();

    // ---- P3: blur e -> sigma, 2x4 micro-tile per thread (all 256 active).
    // 2-row register ring; ky parity static after unroll.
    const float4* e4 = (const float4*)et;
    float acc2[2][4] = {};
    {
        float g0[12], g1[12];
        LOADROW12(g0, e4, (2 * ty) * EQ + tx);        // window row 0
#pragma unroll
        for (int ky = 0; ky < 9; ++ky) {
            float w[9];
#pragma unroll
            for (int kx = 0; kx < 9; ++kx) w[kx] = kw[ky * 9 + kx];
            if ((ky & 1) == 0) {
                LOADROW12(g1, e4, (2 * ty + ky + 1) * EQ + tx);  // row ky+1
#pragma unroll
                for (int kx = 0; kx < 9; ++kx)
#pragma unroll
                    for (int mx = 0; mx < 4; ++mx) {
                        acc2[0][mx] = fmaf(w[kx], g0[mx + kx], acc2[0][mx]);
                        acc2[1][mx] = fmaf(w[kx], g1[mx + kx], acc2[1][mx]);
                    }
            } else {
                LOADROW12(g0, e4, (2 * ty + ky + 1) * EQ + tx);  // row ky+1
#pragma unroll
                for (int kx = 0; kx < 9; ++kx)
#pragma unroll
                    for (int mx = 0; mx < 4; ++mx) {
                        acc2[0][mx] = fmaf(w[kx], g1[mx + kx], acc2[0][mx]);
                        acc2[1][mx] = fmaf(w[kx], g0[mx + kx], acc2[1][mx]);
                    }
            }
        }
    }

    float s = 0.f;
    float* dp = sg + boff + (size_t)(y0 + 2 * ty) * WW + x0 + 4 * tx;
#pragma unroll
    for (int r2 = 0; r2 < 2; ++r2) {
        float4 o;
        o.x = sqrtf(fmaxf(acc2[r2][0], 0.f));
        o.y = sqrtf(fmaxf(acc2[r2][1], 0.f));
        o.z = sqrtf(fmaxf(acc2[r2][2], 0.f));
        o.w = sqrtf(fmaxf(acc2[r2][3], 0.f));
        *(float4*)(dp + r2 * WW) = o;
        s += o.x + o.y + o.z + o.w;
    }
#pragma unroll
    for (int off = 32; off > 0; off >>= 1) s += __shfl_down(s, off);
    if ((tid & 63) == 0) wsum[tid >> 6] = s;
    __syncthreads();
    if (tid == 0)
        psums[blockIdx.z * 128 + blockIdx.y * 8 + blockIdx.x] =
            wsum[0] + wsum[1] + wsum[2] + wsum[3];
}

// ---------------------------------------------------------------------------
// k_norm: out = (x - lm) / max(mean_sigma_b, sigma); reduces 128 partials.
// ---------------------------------------------------------------------------
__global__ __launch_bounds__(256) void k_norm(const float4* __restrict__ x4,
                                              const float4* __restrict__ lm4,
                                              const float4* __restrict__ sg4,
                                              const float* __restrict__ psums,
                                              float4* __restrict__ out4) {
    __shared__ float wsum[4];
    int g = blockIdx.x * 256 + threadIdx.x;
    int b = g >> 16;                                  // g / (HW/4); uniform per block
    float s = 0.f;
    if (threadIdx.x < 128) s = psums[b * 128 + threadIdx.x];
#pragma unroll
    for (int off = 32; off > 0; off >>= 1) s += __shfl_down(s, off);
    if ((threadIdx.x & 63) == 0) wsum[threadIdx.x >> 6] = s;
    __syncthreads();
    float ms = (wsum[0] + wsum[1] + wsum[2] + wsum[3]) * (1.f / (float)HW);

    float4 l = lm4[g];
    float4 sv = sg4[g];
    float i0 = 1.f / fmaxf(ms, sv.x);
    float i1 = 1.f / fmaxf(ms, sv.y);
    float i2 = 1.f / fmaxf(ms, sv.z);
    float i3 = 1.f / fmaxf(ms, sv.w);
    float4 a = x4[3 * g + 0];
    float4 bb = x4[3 * g + 1];
    float4 c = x4[3 * g + 2];
    float4 o0, o1, o2;
    o0.x = (a.x - l.x) * i0;  o0.y = (a.y - l.x) * i0;  o0.z = (a.z - l.x) * i0;
    o0.w = (a.w - l.y) * i1;  o1.x = (bb.x - l.y) * i1; o1.y = (bb.y - l.y) * i1;
    o1.z = (bb.z - l.z) * i2; o1.w = (bb.w - l.z) * i2; o2.x = (c.x - l.z) * i2;
    o2.y = (c.y - l.w) * i3;  o2.z = (c.z - l.w) * i3;  o2.w = (c.w - l.w) * i3;
    out4[3 * g + 0] = o0;
    out4[3 * g + 1] = o1;
    out4[3 * g + 2] = o2;
}

extern "C" void kernel_launch(void* const* d_in, const int* in_sizes, int n_in,
                              void* d_out, int out_size, void* d_ws, size_t ws_size,
                              hipStream_t stream) {
    const float* x = (const float*)d_in[0];
    const float* kw = (const float*)d_in[1];
    float* out = (float*)d_out;
    float* wsp = (float*)d_ws;
    float* lmb = wsp;                                 // NPIX floats
    float* sgb = wsp + (size_t)NPIX;                  // NPIX floats
    float* ps  = wsp + 2 * (size_t)NPIX;              // 4096 floats

    dim3 blk(16, 16);
    dim3 grd(WW / TW, HH / TH, BB);
    k_stats<<<grd, blk, 0, stream>>>(x, kw, lmb, sgb, ps);

    k_norm<<<NPIX / 4 / 256, 256, 0, stream>>>((const float4*)x, (const float4*)lmb,
                                               (const float4*)sgb, ps, (float4*)out);
}

// Round 7
// 282.976 us; speedup vs baseline: 1.8838x; 1.8838x over previous
//
#include <hip/hip_runtime.h>

#define BB 32
#define HH 512
#define WW 512
#define HW (HH * WW)
#define NPIX (BB * HH * WW)

#define TW 64            // tile width
#define TH 32            // tile height
// m buffer: mean over [y0-8..y0+39] x [x0-8..x0+71]; 48 rows, 20 live quads
#define MQ 21            // stride in quads
#define MS 84            // stride in floats
#define MR 48
// lm/e buffer (reused in place): [y0-4..y0+35] x [x0-4..x0+67]; 40 rows
#define EQ 19            // stride in quads
#define ES 76            // stride in floats
#define ER 40

// load 12 consecutive floats (3 quads) from LDS into dst[12]
#define LOADROW12(dst, p4, base)                                              \
    {                                                                         \
        float4 A_ = (p4)[base], B_ = (p4)[(base) + 1], C_ = (p4)[(base) + 2]; \
        (dst)[0] = A_.x; (dst)[1] = A_.y; (dst)[2]  = A_.z; (dst)[3]  = A_.w; \
        (dst)[4] = B_.x; (dst)[5] = B_.y; (dst)[6]  = B_.z; (dst)[7]  = B_.w; \
        (dst)[8] = C_.x; (dst)[9] = C_.y; (dst)[10] = C_.z; (dst)[11] = C_.w; \
    }

// 9x9 blur into acc[4][4]: window rows r0..r0+11, col quads c0..c0+2.
// Sliding 12-row register ring; all reg indices compile-time after unroll.
#define BLUR9(acc, p4, r0, sq, c0)                                            \
    {                                                                         \
        float fw[4][12];                                                      \
        _Pragma("unroll")                                                     \
        for (int j = 0; j < 3; ++j) LOADROW12(fw[j], p4, ((r0) + j) * (sq) + (c0)); \
        _Pragma("unroll")                                                     \
        for (int ky = 0; ky < 9; ++ky) {                                      \
            LOADROW12(fw[(ky + 3) & 3], p4, ((r0) + ky + 3) * (sq) + (c0));   \
            float w[9];                                                       \
            _Pragma("unroll")                                                 \
            for (int kx = 0; kx < 9; ++kx) w[kx] = kw[ky * 9 + kx];           \
            _Pragma("unroll")                                                 \
            for (int my = 0; my < 4; ++my)                                    \
                _Pragma("unroll")                                             \
                for (int kx = 0; kx < 9; ++kx)                                \
                    _Pragma("unroll")                                         \
                    for (int mx = 0; mx < 4; ++mx)                            \
                        acc[my][mx] = fmaf(w[kx], fw[(my + ky) & 3][mx + kx], acc[my][mx]); \
        }                                                                     \
    }

// ---------------------------------------------------------------------------
// k_stats (64x32 tiles), phase-separated to bound register liveness:
//  P1: stage m (48x80) from x            (LDS mt)
//  P2: blur m -> l into e-LDS (+ global lm interior)   [acc dies here]
//  P3: e = max(q - l(2m-l), 0) in place in e-LDS (x reload is L2-warm)
//  P4: blur e (2x4 micro-tiles) -> sigma + per-tile partial sum
// m,q,e never touch HBM. LDS 28.3 KB -> 5 blocks/CU. NO min-waves forcing.
// ---------------------------------------------------------------------------
__global__ __launch_bounds__(256) void k_stats(const float* __restrict__ x,
                                               const float* __restrict__ kw,
                                               float* __restrict__ lm,
                                               float* __restrict__ sg,
                                               float* __restrict__ psums) {
    __shared__ float mt[MR * MS];
    __shared__ float et[ER * ES];
    __shared__ float wsum[4];
    const int tx = threadIdx.x, ty = threadIdx.y;     // 16 x 16
    const int tid = ty * 16 + tx;
    const int x0 = blockIdx.x * TW, y0 = blockIdx.y * TH;
    const size_t boff = (size_t)blockIdx.z * HW;
    const float4* x4 = (const float4*)(x + boff * 3);
    float* lmg = lm + boff;

    // ---- P1: stage m over 48 rows x 20 quads (zero outside image) ----
    for (int i = tid; i < MR * 20; i += 256) {
        int r = i / 20, q = i - r * 20;
        int gy = y0 + r - 8, gx = x0 + 4 * q - 8;
        float4 m = make_float4(0.f, 0.f, 0.f, 0.f);
        if (gy >= 0 && gy < HH && gx >= 0 && gx < WW) {
            int go = (gy * WW + gx) >> 2;
            float4 a = x4[3 * go + 0], b = x4[3 * go + 1], c = x4[3 * go + 2];
            const float t = 1.f / 3.f;
            m.x = (a.x + a.y + a.z) * t;
            m.y = (a.w + b.x + b.y) * t;
            m.z = (b.z + b.w + c.x) * t;
            m.w = (c.y + c.z + c.w) * t;
        }
        *(float4*)&mt[r * MS + 4 * q] = m;
    }
    __syncthreads();

    // ---- P2: blur m -> l into e-LDS; interior l also to global lm.
    // 180 micro-tiles (10x18) of 4x4, one per thread; light epilogue only.
    if (tid < 180) {
        const float4* m4 = (const float4*)mt;
        int tr = tid / 18, q0 = tid - tr * 18;        // tr 0..9, q0 0..17
        float acc[4][4] = {};
        BLUR9(acc, m4, 4 * tr, MQ, q0);
        const int X0 = x0 - 4 + 4 * q0;
        const bool wlm = (tr >= 1) && (tr <= 8) && (q0 >= 1) && (q0 <= 16);
#pragma unroll
        for (int row = 0; row < 4; ++row) {
            float4 l = make_float4(acc[row][0], acc[row][1], acc[row][2], acc[row][3]);
            *(float4*)&et[(4 * tr + row) * ES + 4 * q0] = l;
            if (wlm)
                *(float4*)(lmg + (size_t)(y0 - 4 + 4 * tr + row) * WW + X0) = l;
        }
    }
    __syncthreads();

    // ---- P3: e = max(q - l*(2m - l), 0) in place (position-local) ----
    for (int i = tid; i < ER * 18; i += 256) {
        int r = i / 18, qd = i - r * 18;
        int Y = y0 + r - 4, X = x0 + 4 * qd - 4;
        float4 e = make_float4(0.f, 0.f, 0.f, 0.f);
        if (X >= 0 && X < WW && Y >= 0 && Y < HH) {
            float4 l  = *(const float4*)&et[r * ES + 4 * qd];
            float4 mm = *(const float4*)&mt[(r + 4) * MS + 4 * qd + 4];
            int go = (Y * WW + X) >> 2;
            float4 a = x4[3 * go + 0], b = x4[3 * go + 1], c = x4[3 * go + 2];
            const float t3 = 1.f / 3.f;
            float4 qv;
            qv.x = (a.x * a.x + a.y * a.y + a.z * a.z) * t3;
            qv.y = (a.w * a.w + b.x * b.x + b.y * b.y) * t3;
            qv.z = (b.z * b.z + b.w * b.w + c.x * c.x) * t3;
            qv.w = (c.y * c.y + c.z * c.z + c.w * c.w) * t3;
            e.x = fmaxf(qv.x - l.x * (2.f * mm.x - l.x), 0.f);
            e.y = fmaxf(qv.y - l.y * (2.f * mm.y - l.y), 0.f);
            e.z = fmaxf(qv.z - l.z * (2.f * mm.z - l.z), 0.f);
            e.w = fmaxf(qv.w - l.w * (2.f * mm.w - l.w), 0.f);
        }
        *(float4*)&et[r * ES + 4 * qd] = e;
    }
    __syncthreads();

    // ---- P4: blur e -> sigma, 2x4 micro-tile per thread (all 256 active).
    // 2-row register ring; ky parity static after unroll.
    const float4* e4 = (const float4*)et;
    float acc2[2][4] = {};
    {
        float g0[12], g1[12];
        LOADROW12(g0, e4, (2 * ty) * EQ + tx);        // window row 0
#pragma unroll
        for (int ky = 0; ky < 9; ++ky) {
            float w[9];
#pragma unroll
            for (int kx = 0; kx < 9; ++kx) w[kx] = kw[ky * 9 + kx];
            if ((ky & 1) == 0) {
                LOADROW12(g1, e4, (2 * ty + ky + 1) * EQ + tx);  // row ky+1
#pragma unroll
                for (int kx = 0; kx < 9; ++kx)
#pragma unroll
                    for (int mx = 0; mx < 4; ++mx) {
                        acc2[0][mx] = fmaf(w[kx], g0[mx + kx], acc2[0][mx]);
                        acc2[1][mx] = fmaf(w[kx], g1[mx + kx], acc2[1][mx]);
                    }
            } else {
                LOADROW12(g0, e4, (2 * ty + ky + 1) * EQ + tx);  // row ky+1
#pragma unroll
                for (int kx = 0; kx < 9; ++kx)
#pragma unroll
                    for (int mx = 0; mx < 4; ++mx) {
                        acc2[0][mx] = fmaf(w[kx], g1[mx + kx], acc2[0][mx]);
                        acc2[1][mx] = fmaf(w[kx], g0[mx + kx], acc2[1][mx]);
                    }
            }
        }
    }

    float s = 0.f;
    float* dp = sg + boff + (size_t)(y0 + 2 * ty) * WW + x0 + 4 * tx;
#pragma unroll
    for (int r2 = 0; r2 < 2; ++r2) {
        float4 o;
        o.x = sqrtf(fmaxf(acc2[r2][0], 0.f));
        o.y = sqrtf(fmaxf(acc2[r2][1], 0.f));
        o.z = sqrtf(fmaxf(acc2[r2][2], 0.f));
        o.w = sqrtf(fmaxf(acc2[r2][3], 0.f));
        *(float4*)(dp + r2 * WW) = o;
        s += o.x + o.y + o.z + o.w;
    }
#pragma unroll
    for (int off = 32; off > 0; off >>= 1) s += __shfl_down(s, off);
    if ((tid & 63) == 0) wsum[tid >> 6] = s;
    __syncthreads();
    if (tid == 0)
        psums[blockIdx.z * 128 + blockIdx.y * 8 + blockIdx.x] =
            wsum[0] + wsum[1] + wsum[2] + wsum[3];
}

// ---------------------------------------------------------------------------
// k_norm: out = (x - lm) / max(mean_sigma_b, sigma); reduces 128 partials.
// ---------------------------------------------------------------------------
__global__ __launch_bounds__(256) void k_norm(const float4* __restrict__ x4,
                                              const float4* __restrict__ lm4,
                                              const float4* __restrict__ sg4,
                                              const float* __restrict__ psums,
                                              float4* __restrict__ out4) {
    __shared__ float wsum[4];
    int g = blockIdx.x * 256 + threadIdx.x;
    int b = g >> 16;                                  // g / (HW/4); uniform per block
    float s = 0.f;
    if (threadIdx.x < 128) s = psums[b * 128 + threadIdx.x];
#pragma unroll
    for (int off = 32; off > 0; off >>= 1) s += __shfl_down(s, off);
    if ((threadIdx.x & 63) == 0) wsum[threadIdx.x >> 6] = s;
    __syncthreads();
    float ms = (wsum[0] + wsum[1] + wsum[2] + wsum[3]) * (1.f / (float)HW);

    float4 l = lm4[g];
    float4 sv = sg4[g];
    float i0 = 1.f / fmaxf(ms, sv.x);
    float i1 = 1.f / fmaxf(ms, sv.y);
    float i2 = 1.f / fmaxf(ms, sv.z);
    float i3 = 1.f / fmaxf(ms, sv.w);
    float4 a = x4[3 * g + 0];
    float4 bb = x4[3 * g + 1];
    float4 c = x4[3 * g + 2];
    float4 o0, o1, o2;
    o0.x = (a.x - l.x) * i0;  o0.y = (a.y - l.x) * i0;  o0.z = (a.z - l.x) * i0;
    o0.w = (a.w - l.y) * i1;  o1.x = (bb.x - l.y) * i1; o1.y = (bb.y - l.y) * i1;
    o1.z = (bb.z - l.z) * i2; o1.w = (bb.w - l.z) * i2; o2.x = (c.x - l.z) * i2;
    o2.y = (c.y - l.w) * i3;  o2.z = (c.z - l.w) * i3;  o2.w = (c.w - l.w) * i3;
    out4[3 * g + 0] = o0;
    out4[3 * g + 1] = o1;
    out4[3 * g + 2] = o2;
}

extern "C" void kernel_launch(void* const* d_in, const int* in_sizes, int n_in,
                              void* d_out, int out_size, void* d_ws, size_t ws_size,
                              hipStream_t stream) {
    const float* x = (const float*)d_in[0];
    const float* kw = (const float*)d_in[1];
    float* out = (float*)d_out;
    float* wsp = (float*)d_ws;
    float* lmb = wsp;                                 // NPIX floats
    float* sgb = wsp + (size_t)NPIX;                  // NPIX floats
    float* ps  = wsp + 2 * (size_t)NPIX;              // 4096 floats

    dim3 blk(16, 16);
    dim3 grd(WW / TW, HH / TH, BB);
    k_stats<<<grd, blk, 0, stream>>>(x, kw, lmb, sgb, ps);

    k_norm<<<NPIX / 4 / 256, 256, 0, stream>>>((const float4*)x, (const float4*)lmb,
                                               (const float4*)sgb, ps, (float4*)out);
}

// Round 8
// 273.911 us; speedup vs baseline: 1.9461x; 1.0331x over previous
//
#include <hip/hip_runtime.h>

#define BB 32
#define HH 512
#define WW 512
#define HW (HH * WW)
#define NPIX (BB * HH * WW)

#define TILE 64
#define RG 72            // region rows = TILE + 2*4
#define RQ 20            // row stride in quads (20*16B = 512B -> linear staging)
#define RS 80            // row stride in floats
#define NQ (RG * RQ)     // 1440 staged quads (cols 18,19 are pad, never read)

// load 12 consecutive floats (3 quads) from LDS into dst[12]
#define LOADROW12(dst, p4, base)                                              \
    {                                                                         \
        float4 A_ = (p4)[base], B_ = (p4)[(base) + 1], C_ = (p4)[(base) + 2]; \
        (dst)[0] = A_.x; (dst)[1] = A_.y; (dst)[2]  = A_.z; (dst)[3]  = A_.w; \
        (dst)[4] = B_.x; (dst)[5] = B_.y; (dst)[6]  = B_.z; (dst)[7]  = B_.w; \
        (dst)[8] = C_.x; (dst)[9] = C_.y; (dst)[10] = C_.z; (dst)[11] = C_.w; \
    }

// 9x9 blur of the staged region into acc[4][4] per thread.
// Thread (tx,ty) produces output rows 4ty..4ty+3, cols 4tx..4tx+3.
// Sliding 12-row register ring; all indices compile-time after unroll.
// 8 consecutive lanes read 8 consecutive quads (128B = all 32 banks once).
#define BLUR_4x4(acc, t4, kw, tx, ty)                                         \
    float fw[4][12];                                                          \
    _Pragma("unroll")                                                         \
    for (int j = 0; j < 3; ++j) LOADROW12(fw[j], t4, (4 * (ty) + j) * RQ + (tx)); \
    _Pragma("unroll")                                                         \
    for (int ky = 0; ky < 9; ++ky) {                                          \
        LOADROW12(fw[(ky + 3) & 3], t4, (4 * (ty) + ky + 3) * RQ + (tx));     \
        float w[9];                                                           \
        _Pragma("unroll")                                                     \
        for (int kx = 0; kx < 9; ++kx) w[kx] = kw[ky * 9 + kx];               \
        _Pragma("unroll")                                                     \
        for (int my = 0; my < 4; ++my)                                        \
            _Pragma("unroll")                                                 \
            for (int kx = 0; kx < 9; ++kx)                                    \
                _Pragma("unroll")                                             \
                for (int mx = 0; mx < 4; ++mx)                                \
                    acc[my][mx] = fmaf(w[kx], fw[(my + ky) & 3][mx + kx], acc[my][mx]); \
    }

// ---------------------------------------------------------------------------
// KA: stage m (channel mean of x, on the fly; LINEAR LDS map) -> blur -> lm;
// fused epilogue: e = max(q - lm*(2m - lm), 0) for the interior (x re-read is
// L1/L2-warm). m,q never touch HBM. LDS 23 KB, VGPR ~44 -> 7 blocks/CU.
// ---------------------------------------------------------------------------
__global__ __launch_bounds__(256) void k_lme(const float* __restrict__ x,
                                             const float* __restrict__ kw,
                                             float* __restrict__ lm,
                                             float* __restrict__ eb) {
    __shared__ float mt[RG * RS];
    const int tx = threadIdx.x, ty = threadIdx.y;     // 16 x 16
    const int tid = ty * 16 + tx;
    const int x0 = blockIdx.x * TILE, y0 = blockIdx.y * TILE;
    const size_t boff = (size_t)blockIdx.z * HW;
    const float4* x4 = (const float4*)(x + boff * 3);

    // staged LDS address = 16*i bytes: wave-contiguous, zero-conflict
    for (int i = tid; i < NQ; i += 256) {
        int r = i / 20, q = i - r * 20;
        int gy = y0 + r - 4, gx = x0 + 4 * q - 4;
        float4 m = make_float4(0.f, 0.f, 0.f, 0.f);
        if (gy >= 0 && gy < HH && gx >= 0 && gx < WW) {
            int go = (gy * WW + gx) >> 2;
            float4 a = x4[3 * go + 0];
            float4 b = x4[3 * go + 1];
            float4 c = x4[3 * go + 2];
            const float t = 1.f / 3.f;
            m.x = (a.x + a.y + a.z) * t;
            m.y = (a.w + b.x + b.y) * t;
            m.z = (b.z + b.w + c.x) * t;
            m.w = (c.y + c.z + c.w) * t;
        }
        ((float4*)mt)[i] = m;
    }
    __syncthreads();

    const float4* t4 = (const float4*)mt;
    float acc[4][4] = {};
    __builtin_amdgcn_s_setprio(1);
    BLUR_4x4(acc, t4, kw, tx, ty);
    __builtin_amdgcn_s_setprio(0);

    // write lm and e for the interior 4x4 of this thread
    float* lp = lm + boff + (size_t)(y0 + 4 * ty) * WW + x0 + 4 * tx;
    float* ep = eb + boff + (size_t)(y0 + 4 * ty) * WW + x0 + 4 * tx;
#pragma unroll
    for (int my = 0; my < 4; ++my) {
        float4 l = make_float4(acc[my][0], acc[my][1], acc[my][2], acc[my][3]);
        *(float4*)(lp + my * WW) = l;
        int gy = y0 + 4 * ty + my, gx = x0 + 4 * tx;   // always in-image
        int go = (gy * WW + gx) >> 2;
        float4 a = x4[3 * go + 0];
        float4 b = x4[3 * go + 1];
        float4 c = x4[3 * go + 2];
        const float t = 1.f / 3.f;
        float4 m, q, e;
        m.x = (a.x + a.y + a.z) * t;  q.x = (a.x * a.x + a.y * a.y + a.z * a.z) * t;
        m.y = (a.w + b.x + b.y) * t;  q.y = (a.w * a.w + b.x * b.x + b.y * b.y) * t;
        m.z = (b.z + b.w + c.x) * t;  q.z = (b.z * b.z + b.w * b.w + c.x * c.x) * t;
        m.w = (c.y + c.z + c.w) * t;  q.w = (c.y * c.y + c.z * c.z + c.w * c.w) * t;
        e.x = fmaxf(q.x - l.x * (2.f * m.x - l.x), 0.f);
        e.y = fmaxf(q.y - l.y * (2.f * m.y - l.y), 0.f);
        e.z = fmaxf(q.z - l.z * (2.f * m.z - l.z), 0.f);
        e.w = fmaxf(q.w - l.w * (2.f * m.w - l.w), 0.f);
        *(float4*)(ep + my * WW) = e;
    }
}

// ---------------------------------------------------------------------------
// KB: stage e (zero outside image = 'SAME' padding; LINEAR LDS map) -> blur
// -> sigma; write sg + per-tile partial sum. Staging = 1 float4 per quad.
// ---------------------------------------------------------------------------
__global__ __launch_bounds__(256) void k_sigma(const float* __restrict__ eb,
                                               const float* __restrict__ kw,
                                               float* __restrict__ sg,
                                               float* __restrict__ psums) {
    __shared__ float et[RG * RS];
    __shared__ float wsum[4];
    const int tx = threadIdx.x, ty = threadIdx.y;
    const int tid = ty * 16 + tx;
    const int x0 = blockIdx.x * TILE, y0 = blockIdx.y * TILE;
    const size_t boff = (size_t)blockIdx.z * HW;
    const float4* e4 = (const float4*)(eb + boff);

    for (int i = tid; i < NQ; i += 256) {
        int r = i / 20, q = i - r * 20;
        int gy = y0 + r - 4, gx = x0 + 4 * q - 4;
        float4 e = make_float4(0.f, 0.f, 0.f, 0.f);
        if (gy >= 0 && gy < HH && gx >= 0 && gx < WW)
            e = e4[(gy * WW + gx) >> 2];
        ((float4*)et)[i] = e;
    }
    __syncthreads();

    const float4* t4 = (const float4*)et;
    float acc[4][4] = {};
    __builtin_amdgcn_s_setprio(1);
    BLUR_4x4(acc, t4, kw, tx, ty);
    __builtin_amdgcn_s_setprio(0);

    float s = 0.f;
    float* dp = sg + boff + (size_t)(y0 + 4 * ty) * WW + x0 + 4 * tx;
#pragma unroll
    for (int my = 0; my < 4; ++my) {
        float4 o;
        o.x = sqrtf(fmaxf(acc[my][0], 0.f));
        o.y = sqrtf(fmaxf(acc[my][1], 0.f));
        o.z = sqrtf(fmaxf(acc[my][2], 0.f));
        o.w = sqrtf(fmaxf(acc[my][3], 0.f));
        *(float4*)(dp + my * WW) = o;
        s += o.x + o.y + o.z + o.w;
    }
#pragma unroll
    for (int off = 32; off > 0; off >>= 1) s += __shfl_down(s, off);
    if ((tid & 63) == 0) wsum[tid >> 6] = s;
    __syncthreads();
    if (tid == 0)
        psums[blockIdx.z * 64 + blockIdx.y * 8 + blockIdx.x] =
            wsum[0] + wsum[1] + wsum[2] + wsum[3];
}

// ---------------------------------------------------------------------------
// KC: out = (x - lm) / max(mean_sigma_b, sigma); in-block psums reduction.
// ---------------------------------------------------------------------------
__global__ __launch_bounds__(256) void k_norm(const float4* __restrict__ x4,
                                              const float4* __restrict__ lm4,
                                              const float4* __restrict__ sg4,
                                              const float* __restrict__ psums,
                                              float4* __restrict__ out4) {
    __shared__ float msh;
    int g = blockIdx.x * 256 + threadIdx.x;
    int b = g >> 16;                                  // g / (HW/4); uniform per block
    float s = 0.f;
    if (threadIdx.x < 64) s = psums[b * 64 + threadIdx.x];
#pragma unroll
    for (int off = 32; off > 0; off >>= 1) s += __shfl_down(s, off);
    if (threadIdx.x == 0) msh = s * (1.f / (float)HW);
    __syncthreads();
    float ms = msh;

    float4 l = lm4[g];
    float4 sv = sg4[g];
    float i0 = 1.f / fmaxf(ms, sv.x);
    float i1 = 1.f / fmaxf(ms, sv.y);
    float i2 = 1.f / fmaxf(ms, sv.z);
    float i3 = 1.f / fmaxf(ms, sv.w);
    float4 a = x4[3 * g + 0];
    float4 bb = x4[3 * g + 1];
    float4 c = x4[3 * g + 2];
    float4 o0, o1, o2;
    o0.x = (a.x - l.x) * i0;  o0.y = (a.y - l.x) * i0;  o0.z = (a.z - l.x) * i0;
    o0.w = (a.w - l.y) * i1;  o1.x = (bb.x - l.y) * i1; o1.y = (bb.y - l.y) * i1;
    o1.z = (bb.z - l.z) * i2; o1.w = (bb.w - l.z) * i2; o2.x = (c.x - l.z) * i2;
    o2.y = (c.y - l.w) * i3;  o2.z = (c.z - l.w) * i3;  o2.w = (c.w - l.w) * i3;
    out4[3 * g + 0] = o0;
    out4[3 * g + 1] = o1;
    out4[3 * g + 2] = o2;
}

extern "C" void kernel_launch(void* const* d_in, const int* in_sizes, int n_in,
                              void* d_out, int out_size, void* d_ws, size_t ws_size,
                              hipStream_t stream) {
    const float* x = (const float*)d_in[0];
    const float* kw = (const float*)d_in[1];
    float* out = (float*)d_out;
    float* wsp = (float*)d_ws;
    float* lmb = wsp;                                 // NPIX floats
    float* sgb = wsp + (size_t)NPIX;                  // NPIX floats
    float* ebb = wsp + 2 * (size_t)NPIX;              // NPIX floats
    float* ps  = wsp + 3 * (size_t)NPIX;              // 2048 floats

    dim3 blk(16, 16);
    dim3 grd(WW / TILE, HH / TILE, BB);
    k_lme<<<grd, blk, 0, stream>>>(x, kw, lmb, ebb);
    k_sigma<<<grd, blk, 0, stream>>>(ebb, kw, sgb, ps);

    k_norm<<<NPIX / 4 / 256, 256, 0, stream>>>((const float4*)x, (const float4*)lmb,
                                               (const float4*)sgb, ps, (float4*)out);
}

// Round 9
// 256.924 us; speedup vs baseline: 2.0748x; 1.0661x over previous
//
#include <hip/hip_runtime.h>

#define BB 32
#define HH 512
#define WW 512
#define HW (HH * WW)
#define NPIX (BB * HH * WW)

#define TILE 64
#define RG 72            // region rows = TILE + 2*4
#define RQ 19            // row stride in quads (odd -> conflict-free pad col)
#define RS 76            // row stride in floats
#define NQ (RG * 18)     // 1296 live quads per region

// load 12 consecutive floats (3 quads) from LDS into dst[12]
#define LOADROW12(dst, p4, base)                                              \
    {                                                                         \
        float4 A_ = (p4)[base], B_ = (p4)[(base) + 1], C_ = (p4)[(base) + 2]; \
        (dst)[0] = A_.x; (dst)[1] = A_.y; (dst)[2]  = A_.z; (dst)[3]  = A_.w; \
        (dst)[4] = B_.x; (dst)[5] = B_.y; (dst)[6]  = B_.z; (dst)[7]  = B_.w; \
        (dst)[8] = C_.x; (dst)[9] = C_.y; (dst)[10] = C_.z; (dst)[11] = C_.w; \
    }

// 9x9 blur of the staged region into acc[4][4] per thread (r3-proven form).
// Sliding 12-row register ring; all indices compile-time after unroll.
// 8 consecutive lanes read 8 consecutive quads -> conflict-free ds_read_b128.
#define BLUR_4x4(acc, t4, kw, tx, ty)                                         \
    float fw[4][12];                                                          \
    _Pragma("unroll")                                                         \
    for (int j = 0; j < 3; ++j) LOADROW12(fw[j], t4, (4 * (ty) + j) * RQ + (tx)); \
    _Pragma("unroll")                                                         \
    for (int ky = 0; ky < 9; ++ky) {                                          \
        LOADROW12(fw[(ky + 3) & 3], t4, (4 * (ty) + ky + 3) * RQ + (tx));     \
        float w[9];                                                           \
        _Pragma("unroll")                                                     \
        for (int kx = 0; kx < 9; ++kx) w[kx] = kw[ky * 9 + kx];               \
        _Pragma("unroll")                                                     \
        for (int my = 0; my < 4; ++my)                                        \
            _Pragma("unroll")                                                 \
            for (int kx = 0; kx < 9; ++kx)                                    \
                _Pragma("unroll")                                             \
                for (int mx = 0; mx < 4; ++mx)                                \
                    acc[my][mx] = fmaf(w[kx], fw[(my + ky) & 3][mx + kx], acc[my][mx]); \
    }

// XCD-aware tile swizzle (bijective: 2048 % 8 == 0). Each XCD gets 256
// consecutive logical tiles = 4 whole images -> halo reuse is same-L2.
#define SWIZZLE_TILE(lx, ly, lz)                                              \
    int flat_ = (blockIdx.z * 8 + blockIdx.y) * 8 + blockIdx.x;               \
    int logi_ = (flat_ & 7) * 256 + (flat_ >> 3);                             \
    int lx = logi_ & 7, ly = (logi_ >> 3) & 7, lz = logi_ >> 6;

// ---------------------------------------------------------------------------
// KA: stage m (channel mean of x) with ALL 18 global loads issued up front
// (T14: latency hidden by MLP, not TLP) -> blur -> lm; fused epilogue:
// e = max(q - lm*(2m - lm), 0) for the interior (x re-read L1/L2-warm).
// m,q never touch HBM. LDS 21.9 KB. No setprio, no min-waves forcing.
// ---------------------------------------------------------------------------
__global__ __launch_bounds__(256) void k_lme(const float* __restrict__ x,
                                             const float* __restrict__ kw,
                                             float* __restrict__ lm,
                                             float* __restrict__ eb) {
    __shared__ float mt[RG * RS];
    const int tx = threadIdx.x, ty = threadIdx.y;     // 16 x 16
    const int tid = ty * 16 + tx;
    SWIZZLE_TILE(lx, ly, lz);
    const int x0 = lx * TILE, y0 = ly * TILE;
    const size_t boff = (size_t)lz * HW;
    const float4* x4 = (const float4*)(x + boff * 3);

    // ---- T14 phase 1a: issue all staging loads (statically indexed) ----
    float4 va[6], vb[6], vc[6];
    bool inb[6];
    int ro[6];
#pragma unroll
    for (int it = 0; it < 6; ++it) {
        int i = tid + 256 * it;
        int r = i / 18, q = i - r * 18;
        int gy = y0 + r - 4, gx = x0 + 4 * q - 4;
        inb[it] = (i < NQ) && (gy >= 0) && (gy < HH) && (gx >= 0) && (gx < WW);
        ro[it] = r * RS + 4 * q;
        if (inb[it]) {
            int go = (gy * WW + gx) >> 2;
            va[it] = x4[3 * go + 0];
            vb[it] = x4[3 * go + 1];
            vc[it] = x4[3 * go + 2];
        }
    }
    // ---- T14 phase 1b: compute m, write LDS ----
#pragma unroll
    for (int it = 0; it < 6; ++it) {
        int i = tid + 256 * it;
        if (i < NQ) {
            float4 m = make_float4(0.f, 0.f, 0.f, 0.f);
            if (inb[it]) {
                const float t = 1.f / 3.f;
                m.x = (va[it].x + va[it].y + va[it].z) * t;
                m.y = (va[it].w + vb[it].x + vb[it].y) * t;
                m.z = (vb[it].z + vb[it].w + vc[it].x) * t;
                m.w = (vc[it].y + vc[it].z + vc[it].w) * t;
            }
            *(float4*)&mt[ro[it]] = m;
        }
    }
    __syncthreads();

    const float4* t4 = (const float4*)mt;
    float acc[4][4] = {};
    BLUR_4x4(acc, t4, kw, tx, ty);

    // write lm and e for the interior 4x4 of this thread
    float* lp = lm + boff + (size_t)(y0 + 4 * ty) * WW + x0 + 4 * tx;
    float* ep = eb + boff + (size_t)(y0 + 4 * ty) * WW + x0 + 4 * tx;
#pragma unroll
    for (int my = 0; my < 4; ++my) {
        float4 l = make_float4(acc[my][0], acc[my][1], acc[my][2], acc[my][3]);
        *(float4*)(lp + my * WW) = l;
        int gy = y0 + 4 * ty + my, gx = x0 + 4 * tx;   // always in-image
        int go = (gy * WW + gx) >> 2;
        float4 a = x4[3 * go + 0];
        float4 b = x4[3 * go + 1];
        float4 c = x4[3 * go + 2];
        const float t = 1.f / 3.f;
        float4 m, q, e;
        m.x = (a.x + a.y + a.z) * t;  q.x = (a.x * a.x + a.y * a.y + a.z * a.z) * t;
        m.y = (a.w + b.x + b.y) * t;  q.y = (a.w * a.w + b.x * b.x + b.y * b.y) * t;
        m.z = (b.z + b.w + c.x) * t;  q.z = (b.z * b.z + b.w * b.w + c.x * c.x) * t;
        m.w = (c.y + c.z + c.w) * t;  q.w = (c.y * c.y + c.z * c.z + c.w * c.w) * t;
        e.x = fmaxf(q.x - l.x * (2.f * m.x - l.x), 0.f);
        e.y = fmaxf(q.y - l.y * (2.f * m.y - l.y), 0.f);
        e.z = fmaxf(q.z - l.z * (2.f * m.z - l.z), 0.f);
        e.w = fmaxf(q.w - l.w * (2.f * m.w - l.w), 0.f);
        *(float4*)(ep + my * WW) = e;
    }
}

// ---------------------------------------------------------------------------
// KB: stage e (zero outside image = 'SAME' padding) with all 6 loads issued
// up front (T14) -> blur -> sigma; write sg + per-tile partial sum.
// ---------------------------------------------------------------------------
__global__ __launch_bounds__(256) void k_sigma(const float* __restrict__ eb,
                                               const float* __restrict__ kw,
                                               float* __restrict__ sg,
                                               float* __restrict__ psums) {
    __shared__ float et[RG * RS];
    __shared__ float wsum[4];
    const int tx = threadIdx.x, ty = threadIdx.y;
    const int tid = ty * 16 + tx;
    SWIZZLE_TILE(lx, ly, lz);
    const int x0 = lx * TILE, y0 = ly * TILE;
    const size_t boff = (size_t)lz * HW;
    const float4* e4 = (const float4*)(eb + boff);

    float4 ve[6];
    bool inb[6];
    int ro[6];
#pragma unroll
    for (int it = 0; it < 6; ++it) {
        int i = tid + 256 * it;
        int r = i / 18, q = i - r * 18;
        int gy = y0 + r - 4, gx = x0 + 4 * q - 4;
        inb[it] = (i < NQ) && (gy >= 0) && (gy < HH) && (gx >= 0) && (gx < WW);
        ro[it] = r * RS + 4 * q;
        if (inb[it]) ve[it] = e4[(gy * WW + gx) >> 2];
    }
#pragma unroll
    for (int it = 0; it < 6; ++it) {
        int i = tid + 256 * it;
        if (i < NQ) {
            float4 e = inb[it] ? ve[it] : make_float4(0.f, 0.f, 0.f, 0.f);
            *(float4*)&et[ro[it]] = e;
        }
    }
    __syncthreads();

    const float4* t4 = (const float4*)et;
    float acc[4][4] = {};
    BLUR_4x4(acc, t4, kw, tx, ty);

    float s = 0.f;
    float* dp = sg + boff + (size_t)(y0 + 4 * ty) * WW + x0 + 4 * tx;
#pragma unroll
    for (int my = 0; my < 4; ++my) {
        float4 o;
        o.x = sqrtf(fmaxf(acc[my][0], 0.f));
        o.y = sqrtf(fmaxf(acc[my][1], 0.f));
        o.z = sqrtf(fmaxf(acc[my][2], 0.f));
        o.w = sqrtf(fmaxf(acc[my][3], 0.f));
        *(float4*)(dp + my * WW) = o;
        s += o.x + o.y + o.z + o.w;
    }
#pragma unroll
    for (int off = 32; off > 0; off >>= 1) s += __shfl_down(s, off);
    if ((tid & 63) == 0) wsum[tid >> 6] = s;
    __syncthreads();
    if (tid == 0)
        psums[lz * 64 + ly * 8 + lx] = wsum[0] + wsum[1] + wsum[2] + wsum[3];
}

// ---------------------------------------------------------------------------
// KC: out = (x - lm) / max(mean_sigma_b, sigma); in-block psums reduction.
// At its HBM roofline (~323 MB -> ~51 us).
// ---------------------------------------------------------------------------
__global__ __launch_bounds__(256) void k_norm(const float4* __restrict__ x4,
                                              const float4* __restrict__ lm4,
                                              const float4* __restrict__ sg4,
                                              const float* __restrict__ psums,
                                              float4* __restrict__ out4) {
    __shared__ float msh;
    int g = blockIdx.x * 256 + threadIdx.x;
    int b = g >> 16;                                  // g / (HW/4); uniform per block
    float s = 0.f;
    if (threadIdx.x < 64) s = psums[b * 64 + threadIdx.x];
#pragma unroll
    for (int off = 32; off > 0; off >>= 1) s += __shfl_down(s, off);
    if (threadIdx.x == 0) msh = s * (1.f / (float)HW);
    __syncthreads();
    float ms = msh;

    float4 l = lm4[g];
    float4 sv = sg4[g];
    float i0 = 1.f / fmaxf(ms, sv.x);
    float i1 = 1.f / fmaxf(ms, sv.y);
    float i2 = 1.f / fmaxf(ms, sv.z);
    float i3 = 1.f / fmaxf(ms, sv.w);
    float4 a = x4[3 * g + 0];
    float4 bb = x4[3 * g + 1];
    float4 c = x4[3 * g + 2];
    float4 o0, o1, o2;
    o0.x = (a.x - l.x) * i0;  o0.y = (a.y - l.x) * i0;  o0.z = (a.z - l.x) * i0;
    o0.w = (a.w - l.y) * i1;  o1.x = (bb.x - l.y) * i1; o1.y = (bb.y - l.y) * i1;
    o1.z = (bb.z - l.z) * i2; o1.w = (bb.w - l.z) * i2; o2.x = (c.x - l.z) * i2;
    o2.y = (c.y - l.w) * i3;  o2.z = (c.z - l.w) * i3;  o2.w = (c.w - l.w) * i3;
    out4[3 * g + 0] = o0;
    out4[3 * g + 1] = o1;
    out4[3 * g + 2] = o2;
}

extern "C" void kernel_launch(void* const* d_in, const int* in_sizes, int n_in,
                              void* d_out, int out_size, void* d_ws, size_t ws_size,
                              hipStream_t stream) {
    const float* x = (const float*)d_in[0];
    const float* kw = (const float*)d_in[1];
    float* out = (float*)d_out;
    float* wsp = (float*)d_ws;
    float* lmb = wsp;                                 // NPIX floats
    float* sgb = wsp + (size_t)NPIX;                  // NPIX floats
    float* ebb = wsp + 2 * (size_t)NPIX;              // NPIX floats
    float* ps  = wsp + 3 * (size_t)NPIX;              // 2048 floats

    dim3 blk(16, 16);
    dim3 grd(WW / TILE, HH / TILE, BB);
    k_lme<<<grd, blk, 0, stream>>>(x, kw, lmb, ebb);
    k_sigma<<<grd, blk, 0, stream>>>(ebb, kw, sgb, ps);

    k_norm<<<NPIX / 4 / 256, 256, 0, stream>>>((const float4*)x, (const float4*)lmb,
                                               (const float4*)sgb, ps, (float4*)out);
}